// Round 8
// baseline (505.847 us; speedup 1.0000x reference)
//
#include <hip/hip_runtime.h>
#include <hip/hip_bf16.h>
#include <hip/hip_cooperative_groups.h>

namespace cg = cooperative_groups;

// GCN 2-layer. R8: all preprocessing (hist/scan/scatter/build/castW) fused into
// ONE cooperative kernel with grid.sync() between phases. 9 launches -> 5.

#define FIN 256
#define HDIM 128
#define CDIM 40
#define CAP 8192          // per-bucket edge capacity (mean 4096)

typedef __attribute__((ext_vector_type(8))) short bf16x8;
typedef __attribute__((ext_vector_type(4))) float f32x4;

__device__ inline short f2bf(float f) {               // RNE fp32 -> bf16
    unsigned u = __float_as_uint(f);
    unsigned r = (u + 0x7FFFu + ((u >> 16) & 1u)) >> 16;
    return (short)r;
}
__device__ inline float bflo(unsigned u) { return __uint_as_float(u << 16); }
__device__ inline float bfhi(unsigned u) { return __uint_as_float(u & 0xFFFF0000u); }

// ---- cooperative preprocessing: castW + hist + col-scan + scatter + bucket build ----
// grid = NBUCK blocks x 256 threads (all co-resident: 35.8KB LDS -> 4 blk/CU).
__global__ __launch_bounds__(256) void prep_k(const int* __restrict__ ei,
                                              const float* __restrict__ W1, const float* __restrict__ W2,
                                              int* __restrict__ mat, int* __restrict__ bmem,
                                              int* __restrict__ bcnt, int* __restrict__ csr,
                                              int2* __restrict__ nseg, float* __restrict__ dinv,
                                              float* __restrict__ invd, short* __restrict__ W1T,
                                              short* __restrict__ W2T, int E, int N, int NBUCK, int ec) {
    cg::grid_group grid = cg::this_grid();
    __shared__ int sm[768 + CAP];     // phase A/C: sm[0..511] hist/base; phase D: hist|cur|sc|stage
    const int tid = threadIdx.x;
    const int b = blockIdx.x;
    const int nb = gridDim.x;         // == NBUCK

    // phase A0: weight cast (independent work, done once)
    for (int idx = b * 256 + tid; idx < FIN * HDIM + 48 * HDIM; idx += nb * 256) {
        if (idx < FIN * HDIM) {
            int k = idx >> 7, n = idx & 127;
            W1T[n * FIN + k] = f2bf(W1[idx]);
        } else {
            int j = idx - FIN * HDIM;
            int c = j >> 7, k = j & 127;
            W2T[j] = (c < CDIM) ? f2bf(W2[k * CDIM + c]) : (short)0;
        }
    }

    // phase A: per-block bucket histogram
    for (int t = tid; t < NBUCK; t += 256) sm[t] = 0;
    __syncthreads();
    const int e0 = b * ec;
    const int e1 = min(E, e0 + ec);
    for (int e = e0 + tid; e < e1; e += 256) atomicAdd(&sm[ei[E + e] >> 8], 1);
    __syncthreads();
    for (int t = tid; t < NBUCK; t += 256) mat[b * NBUCK + t] = sm[t];
    grid.sync();

    // phase B: column scan (wave 0 of block b scans bucket-column b)
    if (tid < 64) {
        int carry = b * CAP;
        for (int c0 = 0; c0 < nb; c0 += 64) {
            int idx = c0 + tid;
            int v = (idx < nb) ? mat[idx * NBUCK + b] : 0;
            int incl = v;
#pragma unroll
            for (int off = 1; off < 64; off <<= 1) {
                int t = __shfl_up(incl, off);
                if (tid >= off) incl += t;
            }
            if (idx < nb) mat[idx * NBUCK + b] = carry + (incl - v);
            carry += __shfl(incl, 63);
        }
        if (tid == 0) bcnt[b] = carry - b * CAP;
    }
    grid.sync();

    // phase C: scatter packed records into bucket append regions
    for (int t = tid; t < NBUCK; t += 256) sm[t] = mat[b * NBUCK + t];
    __syncthreads();
    for (int e = e0 + tid; e < e1; e += 256) {
        int s = ei[e];
        int d = ei[E + e];
        int pos = atomicAdd(&sm[d >> 8], 1);
        bmem[pos] = s | ((d & 255) << 20);    // s < 2^20 (N=100000)
    }
    grid.sync();

    // phase D: per-bucket CSR build (block b = bucket b), coalesced writes
    int* hist  = sm;
    int* cur   = sm + 256;
    int* sc    = sm + 512;
    int* stage = sm + 768;
    int cnt = bcnt[b];
    if (cnt > CAP) cnt = CAP;
    const int* src = bmem + b * CAP;
    __syncthreads();                 // phase C LDS reuse
    hist[tid] = 0;
    __syncthreads();
    for (int j = tid; j < cnt; j += 256) atomicAdd(&hist[src[j] >> 20], 1);
    __syncthreads();
    int v = hist[tid];
    sc[tid] = v;
    __syncthreads();
    for (int off = 1; off < 256; off <<= 1) {
        int t = (tid >= off) ? sc[tid - off] : 0;
        __syncthreads();
        sc[tid] += t;
        __syncthreads();
    }
    int excl = sc[tid] - v;
    cur[tid] = excl;
    int i = b * 256 + tid;
    if (i < N) {
        nseg[i] = make_int2(b * CAP + excl, v);
        float dg = (float)(v + 1);
        dinv[i] = rsqrtf(dg);
        invd[i] = 1.0f / dg;
    }
    __syncthreads();
    for (int j = tid; j < cnt; j += 256) {
        int rec = src[j];
        int pos = atomicAdd(&cur[rec >> 20], 1);
        stage[pos] = rec & 0xFFFFF;
    }
    __syncthreads();
    int* dst = csr + b * CAP;
    for (int j = tid; j < cnt; j += 256) dst[j] = stage[j];
}

// GEMM1 (MFMA bf16): T1b = bf16( X(Nx256) @ W1(256x128) ).
#define LDSTRIDE 40
__global__ __launch_bounds__(256) void gemm1_mfma_k(const float* __restrict__ X,
                                                    const short* __restrict__ W1T,
                                                    short* __restrict__ T1b, int N) {
    __shared__ short As[128 * LDSTRIDE];
    __shared__ short Bs[128 * LDSTRIDE];
    const int tid = threadIdx.x;
    const int lane = tid & 63;
    const int wid = tid >> 6;
    const int w0 = wid & 1, w1 = wid >> 1;
    const int quad = lane >> 4;
    const int l16 = lane & 15;
    const int rowbase = blockIdx.x * 128;
    const int sr = tid >> 1;
    const int sh = tid & 1;

    f32x4 acc[4][4];
#pragma unroll
    for (int a = 0; a < 4; a++)
#pragma unroll
        for (int b = 0; b < 4; b++) acc[a][b] = (f32x4){0.f, 0.f, 0.f, 0.f};

    const int arow = min(rowbase + sr, N - 1);
    const float* xsrc = X + (size_t)arow * FIN + sh * 16;
    const int4* bsrc = (const int4*)(W1T + (size_t)sr * FIN + sh * 16);

    for (int k0 = 0; k0 < FIN; k0 += 32) {
        float vals[16];
        *(float4*)&vals[0]  = *(const float4*)(xsrc + k0);
        *(float4*)&vals[4]  = *(const float4*)(xsrc + k0 + 4);
        *(float4*)&vals[8]  = *(const float4*)(xsrc + k0 + 8);
        *(float4*)&vals[12] = *(const float4*)(xsrc + k0 + 12);
        short tmp[16];
#pragma unroll
        for (int c = 0; c < 16; c++) tmp[c] = f2bf(vals[c]);
        ((int4*)&As[sr * LDSTRIDE + sh * 16])[0] = ((int4*)tmp)[0];
        ((int4*)&As[sr * LDSTRIDE + sh * 16])[1] = ((int4*)tmp)[1];
        int4 b0 = bsrc[k0 >> 3];
        int4 b1 = bsrc[(k0 >> 3) + 1];
        ((int4*)&Bs[sr * LDSTRIDE + sh * 16])[0] = b0;
        ((int4*)&Bs[sr * LDSTRIDE + sh * 16])[1] = b1;
        __syncthreads();

        bf16x8 afr[4], bfr[4];
#pragma unroll
        for (int mt = 0; mt < 4; mt++)
            afr[mt] = *(const bf16x8*)&As[(w1 * 64 + mt * 16 + l16) * LDSTRIDE + quad * 8];
#pragma unroll
        for (int nt = 0; nt < 4; nt++)
            bfr[nt] = *(const bf16x8*)&Bs[(w0 * 64 + nt * 16 + l16) * LDSTRIDE + quad * 8];
#pragma unroll
        for (int mt = 0; mt < 4; mt++)
#pragma unroll
            for (int nt = 0; nt < 4; nt++)
                acc[mt][nt] = __builtin_amdgcn_mfma_f32_16x16x32_bf16(afr[mt], bfr[nt], acc[mt][nt], 0, 0, 0);
        __syncthreads();
    }
#pragma unroll
    for (int mt = 0; mt < 4; mt++) {
#pragma unroll
        for (int r = 0; r < 4; r++) {
            int row = rowbase + w1 * 64 + mt * 16 + quad * 4 + r;
            if (row < N) {
#pragma unroll
                for (int nt = 0; nt < 4; nt++) {
                    int col = w0 * 64 + nt * 16 + l16;
                    T1b[(size_t)row * HDIM + col] = f2bf(acc[mt][nt][r]);
                }
            }
        }
    }
}

// agg1: wave/node. Quad-per-neighbor gather (4 rows per dwordx4) unrolled x4.
__global__ __launch_bounds__(256) void agg1_k(const short* __restrict__ T1b, const int2* __restrict__ nseg,
                                              const int* __restrict__ csr, const float* __restrict__ dinv,
                                              const float* __restrict__ invd, const float* __restrict__ b1,
                                              unsigned* __restrict__ Hb, int N) {
    const int lane = threadIdx.x & 63;
    const int quad = lane >> 4;
    const int ql = lane & 15;
    const int i = blockIdx.x * 4 + (threadIdx.x >> 6);
    if (i >= N) return;
    const int2 sg = nseg[i];
    const int e0 = sg.x, deg = sg.y;
    int sv = 0; float wv = 0.f;
    if (lane < deg) { sv = csr[e0 + lane]; wv = dinv[sv]; }

    const uint4* rowp = (const uint4*)T1b;   // 16 uint4 per 256B row
    float acc[8];
#pragma unroll
    for (int t = 0; t < 8; t++) acc[t] = 0.f;

    const int dmain = deg < 64 ? deg : 64;
    for (int j = 0; j < dmain; j += 16) {
        const int i0 = j + quad, i1 = j + 4 + quad, i2 = j + 8 + quad, i3 = j + 12 + quad;
        int s0 = __shfl(sv, i0); int s1 = __shfl(sv, i1);
        int s2 = __shfl(sv, i2); int s3 = __shfl(sv, i3);
        float w0 = __shfl(wv, i0); float w1 = __shfl(wv, i1);
        float w2 = __shfl(wv, i2); float w3 = __shfl(wv, i3);
        w0 = (i0 < dmain) ? w0 : 0.f;
        w1 = (i1 < dmain) ? w1 : 0.f;
        w2 = (i2 < dmain) ? w2 : 0.f;
        w3 = (i3 < dmain) ? w3 : 0.f;
        uint4 u0 = rowp[s0 * 16 + ql];
        uint4 u1 = rowp[s1 * 16 + ql];
        uint4 u2 = rowp[s2 * 16 + ql];
        uint4 u3 = rowp[s3 * 16 + ql];
        acc[0] += w0 * bflo(u0.x) + w1 * bflo(u1.x) + w2 * bflo(u2.x) + w3 * bflo(u3.x);
        acc[1] += w0 * bfhi(u0.x) + w1 * bfhi(u1.x) + w2 * bfhi(u2.x) + w3 * bfhi(u3.x);
        acc[2] += w0 * bflo(u0.y) + w1 * bflo(u1.y) + w2 * bflo(u2.y) + w3 * bflo(u3.y);
        acc[3] += w0 * bfhi(u0.y) + w1 * bfhi(u1.y) + w2 * bfhi(u2.y) + w3 * bfhi(u3.y);
        acc[4] += w0 * bflo(u0.z) + w1 * bflo(u1.z) + w2 * bflo(u2.z) + w3 * bflo(u3.z);
        acc[5] += w0 * bfhi(u0.z) + w1 * bfhi(u1.z) + w2 * bfhi(u2.z) + w3 * bfhi(u3.z);
        acc[6] += w0 * bflo(u0.w) + w1 * bflo(u1.w) + w2 * bflo(u2.w) + w3 * bflo(u3.w);
        acc[7] += w0 * bfhi(u0.w) + w1 * bfhi(u1.w) + w2 * bfhi(u2.w) + w3 * bfhi(u3.w);
    }
    const int eEnd = e0 + deg;
    for (int e = e0 + 64; e < eEnd; e += 4) {          // rare tail deg > 64
        int idx = e + quad;
        int cl = idx < eEnd ? idx : eEnd - 1;
        int sj = csr[cl];
        float wj = (idx < eEnd) ? dinv[sj] : 0.f;
        uint4 u = rowp[sj * 16 + ql];
        acc[0] += wj * bflo(u.x); acc[1] += wj * bfhi(u.x);
        acc[2] += wj * bflo(u.y); acc[3] += wj * bfhi(u.y);
        acc[4] += wj * bflo(u.z); acc[5] += wj * bfhi(u.z);
        acc[6] += wj * bflo(u.w); acc[7] += wj * bfhi(u.w);
    }
#pragma unroll
    for (int t = 0; t < 8; t++) {
        acc[t] += __shfl_xor(acc[t], 16);
        acc[t] += __shfl_xor(acc[t], 32);
    }
    const float di = dinv[i], sf = invd[i];
    uint4 us = rowp[i * 16 + ql];
    float4 bA = *(const float4*)(b1 + ql * 8);
    float4 bB = *(const float4*)(b1 + ql * 8 + 4);
    float o0 = fmaxf(bA.x + sf * bflo(us.x) + di * acc[0], 0.f);
    float o1 = fmaxf(bA.y + sf * bfhi(us.x) + di * acc[1], 0.f);
    float o2 = fmaxf(bA.z + sf * bflo(us.y) + di * acc[2], 0.f);
    float o3 = fmaxf(bA.w + sf * bfhi(us.y) + di * acc[3], 0.f);
    float o4 = fmaxf(bB.x + sf * bflo(us.z) + di * acc[4], 0.f);
    float o5 = fmaxf(bB.y + sf * bfhi(us.z) + di * acc[5], 0.f);
    float o6 = fmaxf(bB.z + sf * bflo(us.w) + di * acc[6], 0.f);
    float o7 = fmaxf(bB.w + sf * bfhi(us.w) + di * acc[7], 0.f);
    uint4 pk;
    pk.x = ((unsigned)(unsigned short)f2bf(o0)) | (((unsigned)(unsigned short)f2bf(o1)) << 16);
    pk.y = ((unsigned)(unsigned short)f2bf(o2)) | (((unsigned)(unsigned short)f2bf(o3)) << 16);
    pk.z = ((unsigned)(unsigned short)f2bf(o4)) | (((unsigned)(unsigned short)f2bf(o5)) << 16);
    pk.w = ((unsigned)(unsigned short)f2bf(o6)) | (((unsigned)(unsigned short)f2bf(o7)) << 16);
    if (quad == 0) ((uint4*)(Hb + (size_t)i * 64))[ql] = pk;
}

// GEMM2 (MFMA bf16): T2b[N][48] bf16 = H(Nx128 bf16) @ W2T(48x128)^T.
__global__ __launch_bounds__(256) void gemm2_mfma_k(const short* __restrict__ Hb,
                                                    const short* __restrict__ W2T,
                                                    short* __restrict__ T2b, int N) {
    __shared__ short As[128 * LDSTRIDE];
    __shared__ short Bs[48 * LDSTRIDE];
    const int tid = threadIdx.x;
    const int lane = tid & 63;
    const int wid = tid >> 6;
    const int quad = lane >> 4;
    const int l16 = lane & 15;
    const int rowbase = blockIdx.x * 128;
    const int sr = tid >> 1;
    const int sh = tid & 1;

    f32x4 acc[2][3];
#pragma unroll
    for (int a = 0; a < 2; a++)
#pragma unroll
        for (int b = 0; b < 3; b++) acc[a][b] = (f32x4){0.f, 0.f, 0.f, 0.f};

    const int arow = min(rowbase + sr, N - 1);
    const int4* asrc = (const int4*)(Hb + (size_t)arow * HDIM + sh * 16);
    const int br = tid >> 1, bh = tid & 1;   // for tid < 96
    const int4* bsrc = (const int4*)(W2T + br * HDIM + bh * 16);

    for (int k0 = 0; k0 < HDIM; k0 += 32) {
        int4 a0 = asrc[k0 >> 3];
        int4 a1 = asrc[(k0 >> 3) + 1];
        ((int4*)&As[sr * LDSTRIDE + sh * 16])[0] = a0;
        ((int4*)&As[sr * LDSTRIDE + sh * 16])[1] = a1;
        if (tid < 96) {
            int4 b0 = bsrc[k0 >> 3];
            int4 b1 = bsrc[(k0 >> 3) + 1];
            ((int4*)&Bs[br * LDSTRIDE + bh * 16])[0] = b0;
            ((int4*)&Bs[br * LDSTRIDE + bh * 16])[1] = b1;
        }
        __syncthreads();
        bf16x8 afr[2], bfr[3];
#pragma unroll
        for (int mt = 0; mt < 2; mt++)
            afr[mt] = *(const bf16x8*)&As[(wid * 32 + mt * 16 + l16) * LDSTRIDE + quad * 8];
#pragma unroll
        for (int nt = 0; nt < 3; nt++)
            bfr[nt] = *(const bf16x8*)&Bs[(nt * 16 + l16) * LDSTRIDE + quad * 8];
#pragma unroll
        for (int mt = 0; mt < 2; mt++)
#pragma unroll
            for (int nt = 0; nt < 3; nt++)
                acc[mt][nt] = __builtin_amdgcn_mfma_f32_16x16x32_bf16(afr[mt], bfr[nt], acc[mt][nt], 0, 0, 0);
        __syncthreads();
    }
#pragma unroll
    for (int mt = 0; mt < 2; mt++) {
#pragma unroll
        for (int r = 0; r < 4; r++) {
            int row = rowbase + wid * 32 + mt * 16 + quad * 4 + r;
            if (row < N) {
#pragma unroll
                for (int nt = 0; nt < 3; nt++) {
                    int col = nt * 16 + l16;
                    T2b[(size_t)row * 48 + col] = f2bf(acc[mt][nt][r]);
                }
            }
        }
    }
}

// agg2: wave/node. bf16 96B rows: oct-per-neighbor (8 rows per dwordx4), unroll x2.
__global__ __launch_bounds__(256) void agg2_k(const short* __restrict__ T2b, const int2* __restrict__ nseg,
                                              const int* __restrict__ csr, const float* __restrict__ dinv,
                                              const float* __restrict__ invd, const float* __restrict__ b2,
                                              float* __restrict__ OUT, int N) {
    const int lane = threadIdx.x & 63;
    const int oct = lane >> 3;
    const int olr = lane & 7;
    const int ol = olr < 6 ? olr : 5;
    const bool act = olr < 6;
    const int i = blockIdx.x * 4 + (threadIdx.x >> 6);
    if (i >= N) return;
    const int2 sg = nseg[i];
    const int e0 = sg.x, deg = sg.y;
    int sv = 0; float wv = 0.f;
    if (lane < deg) { sv = csr[e0 + lane]; wv = dinv[sv]; }

    const uint4* rowp = (const uint4*)T2b;   // 6 uint4 per 96B row
    float acc[8];
#pragma unroll
    for (int t = 0; t < 8; t++) acc[t] = 0.f;

    const int dmain = deg < 64 ? deg : 64;
    for (int j = 0; j < dmain; j += 16) {
        const int i0 = j + oct, i1 = j + 8 + oct;
        int s0 = __shfl(sv, i0); int s1 = __shfl(sv, i1);
        float w0 = __shfl(wv, i0); float w1 = __shfl(wv, i1);
        w0 = (i0 < dmain && act) ? w0 : 0.f;
        w1 = (i1 < dmain && act) ? w1 : 0.f;
        uint4 u0 = rowp[s0 * 6 + ol];
        uint4 u1 = rowp[s1 * 6 + ol];
        acc[0] += w0 * bflo(u0.x) + w1 * bflo(u1.x);
        acc[1] += w0 * bfhi(u0.x) + w1 * bfhi(u1.x);
        acc[2] += w0 * bflo(u0.y) + w1 * bflo(u1.y);
        acc[3] += w0 * bfhi(u0.y) + w1 * bfhi(u1.y);
        acc[4] += w0 * bflo(u0.z) + w1 * bflo(u1.z);
        acc[5] += w0 * bfhi(u0.z) + w1 * bfhi(u1.z);
        acc[6] += w0 * bflo(u0.w) + w1 * bflo(u1.w);
        acc[7] += w0 * bfhi(u0.w) + w1 * bfhi(u1.w);
    }
    const int eEnd = e0 + deg;
    for (int e = e0 + 64; e < eEnd; e += 8) {
        int idx = e + oct;
        int cl = idx < eEnd ? idx : eEnd - 1;
        int sj = csr[cl];
        float wj = (idx < eEnd && act) ? dinv[sj] : 0.f;
        uint4 u = rowp[sj * 6 + ol];
        acc[0] += wj * bflo(u.x); acc[1] += wj * bfhi(u.x);
        acc[2] += wj * bflo(u.y); acc[3] += wj * bfhi(u.y);
        acc[4] += wj * bflo(u.z); acc[5] += wj * bfhi(u.z);
        acc[6] += wj * bflo(u.w); acc[7] += wj * bfhi(u.w);
    }
#pragma unroll
    for (int t = 0; t < 8; t++) {
        acc[t] += __shfl_xor(acc[t], 8);
        acc[t] += __shfl_xor(acc[t], 16);
        acc[t] += __shfl_xor(acc[t], 32);
    }
    if (oct == 0 && olr < 5) {
        const float di = dinv[i], sf = invd[i];
        uint4 us = rowp[i * 6 + olr];
        float4 bA = *(const float4*)(b2 + olr * 8);
        float4 bB = *(const float4*)(b2 + olr * 8 + 4);
        float4 oA, oB;
        oA.x = bA.x + sf * bflo(us.x) + di * acc[0];
        oA.y = bA.y + sf * bfhi(us.x) + di * acc[1];
        oA.z = bA.z + sf * bflo(us.y) + di * acc[2];
        oA.w = bA.w + sf * bfhi(us.y) + di * acc[3];
        oB.x = bB.x + sf * bflo(us.z) + di * acc[4];
        oB.y = bB.y + sf * bfhi(us.z) + di * acc[5];
        oB.z = bB.z + sf * bflo(us.w) + di * acc[6];
        oB.w = bB.w + sf * bfhi(us.w) + di * acc[7];
        *(float4*)(OUT + (size_t)i * CDIM + olr * 8) = oA;
        *(float4*)(OUT + (size_t)i * CDIM + olr * 8 + 4) = oB;
    }
}

extern "C" void kernel_launch(void* const* d_in, const int* in_sizes, int n_in,
                              void* d_out, int out_size, void* d_ws, size_t ws_size,
                              hipStream_t stream) {
    const float* x   = (const float*)d_in[0];
    const int*   ei  = (const int*)d_in[1];     // int32 in harness
    const float* W1  = (const float*)d_in[2];
    const float* b1  = (const float*)d_in[3];
    const float* W2  = (const float*)d_in[4];
    const float* b2  = (const float*)d_in[5];
    float*       out = (float*)d_out;

    const int Hd  = in_sizes[3];            // 128
    const int Fin = in_sizes[2] / Hd;       // 256
    int N   = in_sizes[0] / Fin;            // 100000
    int E   = in_sizes[1] / 2;              // 1600000

    int NBUCK = (N + 255) / 256;            // 391
    int ec    = (E + NBUCK - 1) / NBUCK;    // edges per block in prep

    char* base = (char*)d_ws;
    size_t off = 0;
    auto alloc = [&](size_t bytes) -> void* {
        void* p = base + off;
        off += (bytes + 255) & ~(size_t)255;
        return p;
    };
    // region A: mat+bmem (prep only), overlaid later by t1b (gemm1 onward)
    size_t matB  = (size_t)NBUCK * NBUCK * 4;
    size_t bmemB = (size_t)NBUCK * CAP * 4;
    size_t t1bB  = (size_t)N * HDIM * 2;
    size_t regA  = ((matB + 255) & ~(size_t)255) + bmemB;
    if (t1bB > regA) regA = t1bB;
    char* pA = (char*)alloc(regA);
    int*   mat  = (int*)pA;
    int*   bmem = (int*)(pA + ((matB + 255) & ~(size_t)255));
    short* t1b  = (short*)pA;

    int*      bcnt = (int*)alloc((size_t)NBUCK * 4);
    int*      csr  = (int*)alloc((size_t)NBUCK * CAP * 4);
    int2*     nseg = (int2*)alloc((size_t)N * 8);
    float*    dinv = (float*)alloc((size_t)N * 4);
    float*    invd = (float*)alloc((size_t)N * 4);
    short*    W1T  = (short*)alloc((size_t)HDIM * FIN * 2);
    short*    W2T  = (short*)alloc((size_t)48 * HDIM * 2);
    unsigned* hb   = (unsigned*)alloc((size_t)N * HDIM * 2);
    short*    t2b  = (short*)alloc((size_t)N * 48 * 2);

    void* args[] = {(void*)&ei, (void*)&W1, (void*)&W2, (void*)&mat, (void*)&bmem,
                    (void*)&bcnt, (void*)&csr, (void*)&nseg, (void*)&dinv, (void*)&invd,
                    (void*)&W1T, (void*)&W2T, (void*)&E, (void*)&N, (void*)&NBUCK, (void*)&ec};
    hipLaunchCooperativeKernel((void*)prep_k, dim3(NBUCK), dim3(256), args, 0, stream);

    gemm1_mfma_k<<<(N + 127) / 128, 256, 0, stream>>>(x, W1T, t1b, N);
    agg1_k<<<(N + 3) / 4, 256, 0, stream>>>(t1b, nseg, csr, dinv, invd, b1, hb, N);
    gemm2_mfma_k<<<(N + 127) / 128, 256, 0, stream>>>((const short*)hb, W2T, t2b, N);
    agg2_k<<<(N + 3) / 4, 256, 0, stream>>>(t2b, nseg, csr, dinv, invd, b2, out, N);
}

// Round 9
// 332.592 us; speedup vs baseline: 1.5209x; 1.5209x over previous
//
#include <hip/hip_runtime.h>
#include <hip/hip_bf16.h>

// GCN 2-layer. R9: revert R8 coop fusion (regressed). R7 structure +
// (a) single-pass scatter w/ global bucket atomics (kills hist+scan kernels),
// (b) castW folded into p2_build, (c) float2 packed-FMA accumulate in agg1/agg2.

#define FIN 256
#define HDIM 128
#define CDIM 40
#define CAP 8192          // per-bucket edge capacity (mean 4096)
#define EC 8192           // edges per block in scatter

typedef __attribute__((ext_vector_type(8))) short bf16x8;
typedef __attribute__((ext_vector_type(4))) float f32x4;
typedef __attribute__((ext_vector_type(2))) float f32x2;

__device__ inline short f2bf(float f) {               // RNE fp32 -> bf16
    unsigned u = __float_as_uint(f);
    unsigned r = (u + 0x7FFFu + ((u >> 16) & 1u)) >> 16;
    return (short)r;
}
__device__ inline float bflo(unsigned u) { return __uint_as_float(u << 16); }
__device__ inline float bfhi(unsigned u) { return __uint_as_float(u & 0xFFFF0000u); }
__device__ inline f32x2 unpk(unsigned u) { return (f32x2){bflo(u), bfhi(u)}; }

// ---- scatter: per-block LDS hist -> global bucket-base alloc -> scatter ----
__global__ __launch_bounds__(1024) void scatter_k(const int* __restrict__ ei, int* __restrict__ gcnt,
                                                  int* __restrict__ bmem, int E, int NBUCK) {
    __shared__ int hist[512];
    __shared__ int base[512];
    const int tid = threadIdx.x;
    for (int t = tid; t < NBUCK; t += 1024) hist[t] = 0;
    __syncthreads();
    const int e0 = blockIdx.x * EC;
    const int e1 = min(E, e0 + EC);
    for (int e = e0 + tid; e < e1; e += 1024) atomicAdd(&hist[ei[E + e] >> 8], 1);
    __syncthreads();
    for (int t = tid; t < NBUCK; t += 1024) base[t] = atomicAdd(&gcnt[t], hist[t]);
    __syncthreads();
    for (int e = e0 + tid; e < e1; e += 1024) {
        int s = ei[e];
        int d = ei[E + e];
        int b = d >> 8;
        int pos = atomicAdd(&base[b], 1);
        bmem[b * CAP + pos] = s | ((d & 255) << 20);   // s < 2^20 (N=100000)
    }
}

// ---- per-bucket CSR build (+ folded weight cast), coalesced writes ----
__global__ __launch_bounds__(256) void p2_build_k(const int* __restrict__ bmem, const int* __restrict__ bcnt,
                                                  int* __restrict__ csr, int2* __restrict__ nseg,
                                                  float* __restrict__ dinv, float* __restrict__ invd,
                                                  const float* __restrict__ W1, const float* __restrict__ W2,
                                                  short* __restrict__ W1T, short* __restrict__ W2T, int N) {
    __shared__ int hist[256], cur[256], sc[256];
    __shared__ int stage[CAP];
    const int b = blockIdx.x;
    const int tid = threadIdx.x;

    // folded castW: grid-stride over both weight matrices
    for (int idx = b * 256 + tid; idx < FIN * HDIM + 48 * HDIM; idx += gridDim.x * 256) {
        if (idx < FIN * HDIM) {
            int k = idx >> 7, n = idx & 127;
            W1T[n * FIN + k] = f2bf(W1[idx]);
        } else {
            int j = idx - FIN * HDIM;
            int c = j >> 7, k = j & 127;
            W2T[j] = (c < CDIM) ? f2bf(W2[k * CDIM + c]) : (short)0;
        }
    }

    int cnt = bcnt[b];
    if (cnt > CAP) cnt = CAP;
    const int* src = bmem + b * CAP;
    hist[tid] = 0;
    __syncthreads();
    for (int j = tid; j < cnt; j += 256) atomicAdd(&hist[src[j] >> 20], 1);
    __syncthreads();
    int v = hist[tid];
    sc[tid] = v;
    __syncthreads();
    for (int off = 1; off < 256; off <<= 1) {
        int t = (tid >= off) ? sc[tid - off] : 0;
        __syncthreads();
        sc[tid] += t;
        __syncthreads();
    }
    int excl = sc[tid] - v;
    cur[tid] = excl;
    int i = b * 256 + tid;
    if (i < N) {
        nseg[i] = make_int2(b * CAP + excl, v);
        float dg = (float)(v + 1);
        dinv[i] = rsqrtf(dg);
        invd[i] = 1.0f / dg;
    }
    __syncthreads();
    for (int j = tid; j < cnt; j += 256) {
        int rec = src[j];
        int pos = atomicAdd(&cur[rec >> 20], 1);
        stage[pos] = rec & 0xFFFFF;
    }
    __syncthreads();
    int* dst = csr + b * CAP;
    for (int j = tid; j < cnt; j += 256) dst[j] = stage[j];
}

// GEMM1 (MFMA bf16): T1b = bf16( X(Nx256) @ W1(256x128) ).
#define LDSTRIDE 40
__global__ __launch_bounds__(256) void gemm1_mfma_k(const float* __restrict__ X,
                                                    const short* __restrict__ W1T,
                                                    short* __restrict__ T1b, int N) {
    __shared__ short As[128 * LDSTRIDE];
    __shared__ short Bs[128 * LDSTRIDE];
    const int tid = threadIdx.x;
    const int lane = tid & 63;
    const int wid = tid >> 6;
    const int w0 = wid & 1, w1 = wid >> 1;
    const int quad = lane >> 4;
    const int l16 = lane & 15;
    const int rowbase = blockIdx.x * 128;
    const int sr = tid >> 1;
    const int sh = tid & 1;

    f32x4 acc[4][4];
#pragma unroll
    for (int a = 0; a < 4; a++)
#pragma unroll
        for (int b = 0; b < 4; b++) acc[a][b] = (f32x4){0.f, 0.f, 0.f, 0.f};

    const int arow = min(rowbase + sr, N - 1);
    const float* xsrc = X + (size_t)arow * FIN + sh * 16;
    const int4* bsrc = (const int4*)(W1T + (size_t)sr * FIN + sh * 16);

    for (int k0 = 0; k0 < FIN; k0 += 32) {
        float vals[16];
        *(float4*)&vals[0]  = *(const float4*)(xsrc + k0);
        *(float4*)&vals[4]  = *(const float4*)(xsrc + k0 + 4);
        *(float4*)&vals[8]  = *(const float4*)(xsrc + k0 + 8);
        *(float4*)&vals[12] = *(const float4*)(xsrc + k0 + 12);
        short tmp[16];
#pragma unroll
        for (int c = 0; c < 16; c++) tmp[c] = f2bf(vals[c]);
        ((int4*)&As[sr * LDSTRIDE + sh * 16])[0] = ((int4*)tmp)[0];
        ((int4*)&As[sr * LDSTRIDE + sh * 16])[1] = ((int4*)tmp)[1];
        int4 b0 = bsrc[k0 >> 3];
        int4 b1 = bsrc[(k0 >> 3) + 1];
        ((int4*)&Bs[sr * LDSTRIDE + sh * 16])[0] = b0;
        ((int4*)&Bs[sr * LDSTRIDE + sh * 16])[1] = b1;
        __syncthreads();

        bf16x8 afr[4], bfr[4];
#pragma unroll
        for (int mt = 0; mt < 4; mt++)
            afr[mt] = *(const bf16x8*)&As[(w1 * 64 + mt * 16 + l16) * LDSTRIDE + quad * 8];
#pragma unroll
        for (int nt = 0; nt < 4; nt++)
            bfr[nt] = *(const bf16x8*)&Bs[(w0 * 64 + nt * 16 + l16) * LDSTRIDE + quad * 8];
#pragma unroll
        for (int mt = 0; mt < 4; mt++)
#pragma unroll
            for (int nt = 0; nt < 4; nt++)
                acc[mt][nt] = __builtin_amdgcn_mfma_f32_16x16x32_bf16(afr[mt], bfr[nt], acc[mt][nt], 0, 0, 0);
        __syncthreads();
    }
#pragma unroll
    for (int mt = 0; mt < 4; mt++) {
#pragma unroll
        for (int r = 0; r < 4; r++) {
            int row = rowbase + w1 * 64 + mt * 16 + quad * 4 + r;
            if (row < N) {
#pragma unroll
                for (int nt = 0; nt < 4; nt++) {
                    int col = w0 * 64 + nt * 16 + l16;
                    T1b[(size_t)row * HDIM + col] = f2bf(acc[mt][nt][r]);
                }
            }
        }
    }
}

// agg1: wave/node. Quad-per-neighbor gather unrolled x4, float2 packed FMA.
__global__ __launch_bounds__(256) void agg1_k(const short* __restrict__ T1b, const int2* __restrict__ nseg,
                                              const int* __restrict__ csr, const float* __restrict__ dinv,
                                              const float* __restrict__ invd, const float* __restrict__ b1,
                                              unsigned* __restrict__ Hb, int N) {
    const int lane = threadIdx.x & 63;
    const int quad = lane >> 4;
    const int ql = lane & 15;
    const int i = blockIdx.x * 4 + (threadIdx.x >> 6);
    if (i >= N) return;
    const int2 sg = nseg[i];
    const int e0 = sg.x, deg = sg.y;
    int sv = 0; float wv = 0.f;
    if (lane < deg) { sv = csr[e0 + lane]; wv = dinv[sv]; }

    const uint4* rowp = (const uint4*)T1b;   // 16 uint4 per 256B row
    f32x2 acc[4];
#pragma unroll
    for (int t = 0; t < 4; t++) acc[t] = (f32x2){0.f, 0.f};

    const int dmain = deg < 64 ? deg : 64;
    for (int j = 0; j < dmain; j += 16) {
        const int i0 = j + quad, i1 = j + 4 + quad, i2 = j + 8 + quad, i3 = j + 12 + quad;
        int s0 = __shfl(sv, i0); int s1 = __shfl(sv, i1);
        int s2 = __shfl(sv, i2); int s3 = __shfl(sv, i3);
        float w0 = __shfl(wv, i0); float w1 = __shfl(wv, i1);
        float w2 = __shfl(wv, i2); float w3 = __shfl(wv, i3);
        w0 = (i0 < dmain) ? w0 : 0.f;
        w1 = (i1 < dmain) ? w1 : 0.f;
        w2 = (i2 < dmain) ? w2 : 0.f;
        w3 = (i3 < dmain) ? w3 : 0.f;
        uint4 u0 = rowp[s0 * 16 + ql];
        uint4 u1 = rowp[s1 * 16 + ql];
        uint4 u2 = rowp[s2 * 16 + ql];
        uint4 u3 = rowp[s3 * 16 + ql];
        f32x2 W0 = (f32x2){w0, w0}, W1v = (f32x2){w1, w1}, W2v = (f32x2){w2, w2}, W3v = (f32x2){w3, w3};
        acc[0] += W0 * unpk(u0.x) + W1v * unpk(u1.x) + W2v * unpk(u2.x) + W3v * unpk(u3.x);
        acc[1] += W0 * unpk(u0.y) + W1v * unpk(u1.y) + W2v * unpk(u2.y) + W3v * unpk(u3.y);
        acc[2] += W0 * unpk(u0.z) + W1v * unpk(u1.z) + W2v * unpk(u2.z) + W3v * unpk(u3.z);
        acc[3] += W0 * unpk(u0.w) + W1v * unpk(u1.w) + W2v * unpk(u2.w) + W3v * unpk(u3.w);
    }
    const int eEnd = e0 + deg;
    for (int e = e0 + 64; e < eEnd; e += 4) {          // rare tail deg > 64
        int idx = e + quad;
        int cl = idx < eEnd ? idx : eEnd - 1;
        int sj = csr[cl];
        float wj = (idx < eEnd) ? dinv[sj] : 0.f;
        uint4 u = rowp[sj * 16 + ql];
        f32x2 Wj = (f32x2){wj, wj};
        acc[0] += Wj * unpk(u.x);
        acc[1] += Wj * unpk(u.y);
        acc[2] += Wj * unpk(u.z);
        acc[3] += Wj * unpk(u.w);
    }
#pragma unroll
    for (int t = 0; t < 4; t++) {
        acc[t].x += __shfl_xor(acc[t].x, 16); acc[t].y += __shfl_xor(acc[t].y, 16);
        acc[t].x += __shfl_xor(acc[t].x, 32); acc[t].y += __shfl_xor(acc[t].y, 32);
    }
    const float di = dinv[i], sf = invd[i];
    uint4 us = rowp[i * 16 + ql];
    float4 bA = *(const float4*)(b1 + ql * 8);
    float4 bB = *(const float4*)(b1 + ql * 8 + 4);
    float o0 = fmaxf(bA.x + sf * bflo(us.x) + di * acc[0].x, 0.f);
    float o1 = fmaxf(bA.y + sf * bfhi(us.x) + di * acc[0].y, 0.f);
    float o2 = fmaxf(bA.z + sf * bflo(us.y) + di * acc[1].x, 0.f);
    float o3 = fmaxf(bA.w + sf * bfhi(us.y) + di * acc[1].y, 0.f);
    float o4 = fmaxf(bB.x + sf * bflo(us.z) + di * acc[2].x, 0.f);
    float o5 = fmaxf(bB.y + sf * bfhi(us.z) + di * acc[2].y, 0.f);
    float o6 = fmaxf(bB.z + sf * bflo(us.w) + di * acc[3].x, 0.f);
    float o7 = fmaxf(bB.w + sf * bfhi(us.w) + di * acc[3].y, 0.f);
    uint4 pk;
    pk.x = ((unsigned)(unsigned short)f2bf(o0)) | (((unsigned)(unsigned short)f2bf(o1)) << 16);
    pk.y = ((unsigned)(unsigned short)f2bf(o2)) | (((unsigned)(unsigned short)f2bf(o3)) << 16);
    pk.z = ((unsigned)(unsigned short)f2bf(o4)) | (((unsigned)(unsigned short)f2bf(o5)) << 16);
    pk.w = ((unsigned)(unsigned short)f2bf(o6)) | (((unsigned)(unsigned short)f2bf(o7)) << 16);
    if (quad == 0) ((uint4*)(Hb + (size_t)i * 64))[ql] = pk;
}

// GEMM2 (MFMA bf16): T2b[N][48] bf16 = H(Nx128 bf16) @ W2T(48x128)^T.
__global__ __launch_bounds__(256) void gemm2_mfma_k(const short* __restrict__ Hb,
                                                    const short* __restrict__ W2T,
                                                    short* __restrict__ T2b, int N) {
    __shared__ short As[128 * LDSTRIDE];
    __shared__ short Bs[48 * LDSTRIDE];
    const int tid = threadIdx.x;
    const int lane = tid & 63;
    const int wid = tid >> 6;
    const int quad = lane >> 4;
    const int l16 = lane & 15;
    const int rowbase = blockIdx.x * 128;
    const int sr = tid >> 1;
    const int sh = tid & 1;

    f32x4 acc[2][3];
#pragma unroll
    for (int a = 0; a < 2; a++)
#pragma unroll
        for (int b = 0; b < 3; b++) acc[a][b] = (f32x4){0.f, 0.f, 0.f, 0.f};

    const int arow = min(rowbase + sr, N - 1);
    const int4* asrc = (const int4*)(Hb + (size_t)arow * HDIM + sh * 16);
    const int br = tid >> 1, bh = tid & 1;   // for tid < 96
    const int4* bsrc = (const int4*)(W2T + br * HDIM + bh * 16);

    for (int k0 = 0; k0 < HDIM; k0 += 32) {
        int4 a0 = asrc[k0 >> 3];
        int4 a1 = asrc[(k0 >> 3) + 1];
        ((int4*)&As[sr * LDSTRIDE + sh * 16])[0] = a0;
        ((int4*)&As[sr * LDSTRIDE + sh * 16])[1] = a1;
        if (tid < 96) {
            int4 b0 = bsrc[k0 >> 3];
            int4 b1 = bsrc[(k0 >> 3) + 1];
            ((int4*)&Bs[br * LDSTRIDE + bh * 16])[0] = b0;
            ((int4*)&Bs[br * LDSTRIDE + bh * 16])[1] = b1;
        }
        __syncthreads();
        bf16x8 afr[2], bfr[3];
#pragma unroll
        for (int mt = 0; mt < 2; mt++)
            afr[mt] = *(const bf16x8*)&As[(wid * 32 + mt * 16 + l16) * LDSTRIDE + quad * 8];
#pragma unroll
        for (int nt = 0; nt < 3; nt++)
            bfr[nt] = *(const bf16x8*)&Bs[(nt * 16 + l16) * LDSTRIDE + quad * 8];
#pragma unroll
        for (int mt = 0; mt < 2; mt++)
#pragma unroll
            for (int nt = 0; nt < 3; nt++)
                acc[mt][nt] = __builtin_amdgcn_mfma_f32_16x16x32_bf16(afr[mt], bfr[nt], acc[mt][nt], 0, 0, 0);
        __syncthreads();
    }
#pragma unroll
    for (int mt = 0; mt < 2; mt++) {
#pragma unroll
        for (int r = 0; r < 4; r++) {
            int row = rowbase + wid * 32 + mt * 16 + quad * 4 + r;
            if (row < N) {
#pragma unroll
                for (int nt = 0; nt < 3; nt++) {
                    int col = nt * 16 + l16;
                    T2b[(size_t)row * 48 + col] = f2bf(acc[mt][nt][r]);
                }
            }
        }
    }
}

// agg2: wave/node. bf16 96B rows: oct-per-neighbor, unroll x2, float2 packed FMA.
__global__ __launch_bounds__(256) void agg2_k(const short* __restrict__ T2b, const int2* __restrict__ nseg,
                                              const int* __restrict__ csr, const float* __restrict__ dinv,
                                              const float* __restrict__ invd, const float* __restrict__ b2,
                                              float* __restrict__ OUT, int N) {
    const int lane = threadIdx.x & 63;
    const int oct = lane >> 3;
    const int olr = lane & 7;
    const int ol = olr < 6 ? olr : 5;
    const bool act = olr < 6;
    const int i = blockIdx.x * 4 + (threadIdx.x >> 6);
    if (i >= N) return;
    const int2 sg = nseg[i];
    const int e0 = sg.x, deg = sg.y;
    int sv = 0; float wv = 0.f;
    if (lane < deg) { sv = csr[e0 + lane]; wv = dinv[sv]; }

    const uint4* rowp = (const uint4*)T2b;   // 6 uint4 per 96B row
    f32x2 acc[4];
#pragma unroll
    for (int t = 0; t < 4; t++) acc[t] = (f32x2){0.f, 0.f};

    const int dmain = deg < 64 ? deg : 64;
    for (int j = 0; j < dmain; j += 16) {
        const int i0 = j + oct, i1 = j + 8 + oct;
        int s0 = __shfl(sv, i0); int s1 = __shfl(sv, i1);
        float w0 = __shfl(wv, i0); float w1 = __shfl(wv, i1);
        w0 = (i0 < dmain && act) ? w0 : 0.f;
        w1 = (i1 < dmain && act) ? w1 : 0.f;
        uint4 u0 = rowp[s0 * 6 + ol];
        uint4 u1 = rowp[s1 * 6 + ol];
        f32x2 W0 = (f32x2){w0, w0}, W1v = (f32x2){w1, w1};
        acc[0] += W0 * unpk(u0.x) + W1v * unpk(u1.x);
        acc[1] += W0 * unpk(u0.y) + W1v * unpk(u1.y);
        acc[2] += W0 * unpk(u0.z) + W1v * unpk(u1.z);
        acc[3] += W0 * unpk(u0.w) + W1v * unpk(u1.w);
    }
    const int eEnd = e0 + deg;
    for (int e = e0 + 64; e < eEnd; e += 8) {
        int idx = e + oct;
        int cl = idx < eEnd ? idx : eEnd - 1;
        int sj = csr[cl];
        float wj = (idx < eEnd && act) ? dinv[sj] : 0.f;
        uint4 u = rowp[sj * 6 + ol];
        f32x2 Wj = (f32x2){wj, wj};
        acc[0] += Wj * unpk(u.x);
        acc[1] += Wj * unpk(u.y);
        acc[2] += Wj * unpk(u.z);
        acc[3] += Wj * unpk(u.w);
    }
#pragma unroll
    for (int t = 0; t < 4; t++) {
        acc[t].x += __shfl_xor(acc[t].x, 8);  acc[t].y += __shfl_xor(acc[t].y, 8);
        acc[t].x += __shfl_xor(acc[t].x, 16); acc[t].y += __shfl_xor(acc[t].y, 16);
        acc[t].x += __shfl_xor(acc[t].x, 32); acc[t].y += __shfl_xor(acc[t].y, 32);
    }
    if (oct == 0 && olr < 5) {
        const float di = dinv[i], sf = invd[i];
        uint4 us = rowp[i * 6 + olr];
        float4 bA = *(const float4*)(b2 + olr * 8);
        float4 bB = *(const float4*)(b2 + olr * 8 + 4);
        float4 oA, oB;
        oA.x = bA.x + sf * bflo(us.x) + di * acc[0].x;
        oA.y = bA.y + sf * bfhi(us.x) + di * acc[0].y;
        oA.z = bA.z + sf * bflo(us.y) + di * acc[1].x;
        oA.w = bA.w + sf * bfhi(us.y) + di * acc[1].y;
        oB.x = bB.x + sf * bflo(us.z) + di * acc[2].x;
        oB.y = bB.y + sf * bfhi(us.z) + di * acc[2].y;
        oB.z = bB.z + sf * bflo(us.w) + di * acc[3].x;
        oB.w = bB.w + sf * bfhi(us.w) + di * acc[3].y;
        *(float4*)(OUT + (size_t)i * CDIM + olr * 8) = oA;
        *(float4*)(OUT + (size_t)i * CDIM + olr * 8 + 4) = oB;
    }
}

extern "C" void kernel_launch(void* const* d_in, const int* in_sizes, int n_in,
                              void* d_out, int out_size, void* d_ws, size_t ws_size,
                              hipStream_t stream) {
    const float* x   = (const float*)d_in[0];
    const int*   ei  = (const int*)d_in[1];     // int32 in harness
    const float* W1  = (const float*)d_in[2];
    const float* b1  = (const float*)d_in[3];
    const float* W2  = (const float*)d_in[4];
    const float* b2  = (const float*)d_in[5];
    float*       out = (float*)d_out;

    const int Hd  = in_sizes[3];            // 128
    const int Fin = in_sizes[2] / Hd;       // 256
    const int N   = in_sizes[0] / Fin;      // 100000
    const int E   = in_sizes[1] / 2;        // 1600000

    const int NBUCK = (N + 255) / 256;      // 391
    const int NB1   = (E + EC - 1) / EC;    // 196

    char* base = (char*)d_ws;
    size_t off = 0;
    auto alloc = [&](size_t bytes) -> void* {
        void* p = base + off;
        off += (bytes + 255) & ~(size_t)255;
        return p;
    };
    // region A: bmem (prep only), overlaid later by t1b (gemm1 onward)
    size_t bmemB = (size_t)NBUCK * CAP * 4;
    size_t t1bB  = (size_t)N * HDIM * 2;
    size_t regA  = bmemB > t1bB ? bmemB : t1bB;
    char* pA = (char*)alloc(regA);
    int*   bmem = (int*)pA;
    short* t1b  = (short*)pA;

    int*      gcnt = (int*)alloc((size_t)NBUCK * 4);
    int*      csr  = (int*)alloc((size_t)NBUCK * CAP * 4);
    int2*     nseg = (int2*)alloc((size_t)N * 8);
    float*    dinv = (float*)alloc((size_t)N * 4);
    float*    invd = (float*)alloc((size_t)N * 4);
    short*    W1T  = (short*)alloc((size_t)HDIM * FIN * 2);
    short*    W2T  = (short*)alloc((size_t)48 * HDIM * 2);
    unsigned* hb   = (unsigned*)alloc((size_t)N * HDIM * 2);
    short*    t2b  = (short*)alloc((size_t)N * 48 * 2);

    hipMemsetAsync(gcnt, 0, (size_t)NBUCK * 4, stream);
    scatter_k<<<NB1, 1024, 0, stream>>>(ei, gcnt, bmem, E, NBUCK);
    p2_build_k<<<NBUCK, 256, 0, stream>>>(bmem, gcnt, csr, nseg, dinv, invd, W1, W2, W1T, W2T, N);

    gemm1_mfma_k<<<(N + 127) / 128, 256, 0, stream>>>(x, W1T, t1b, N);
    agg1_k<<<(N + 3) / 4, 256, 0, stream>>>(t1b, nseg, csr, dinv, invd, b1, hb, N);
    gemm2_mfma_k<<<(N + 127) / 128, 256, 0, stream>>>((const short*)hb, W2T, t2b, N);
    agg2_k<<<(N + 3) / 4, 256, 0, stream>>>(t2b, nseg, csr, dinv, invd, b2, out, N);
}